// Round 1
// baseline (1964.942 us; speedup 1.0000x reference)
//
#include <hip/hip_runtime.h>
#include <hip/hip_bf16.h>

#define B_   64
#define T_   512
#define N_   14
#define F_   16
#define H_   128
#define G4_  512   // 4*H

// ---------------------------------------------------------------------------
// LSTM kernel: one block per sequence (m = b*N + n). 512 threads, thread g
// owns gate row g (W_hh row in registers). h/c state + x staged in LDS.
// ---------------------------------------------------------------------------
__global__ __launch_bounds__(512, 1) void lstm_kernel(
    const float* __restrict__ x,      // [B, T, N, F]
    const float* __restrict__ W_ih,   // [4H, F]
    const float* __restrict__ W_hh,   // [4H, H]
    const float* __restrict__ b_ih,   // [4H]
    const float* __restrict__ b_hh,   // [4H]
    float* __restrict__ h_out)        // [B*N, H]
{
    const int m = blockIdx.x;          // sequence index
    const int b = m / N_;
    const int n = m % N_;
    const int g = threadIdx.x;         // gate row 0..511

    __shared__ float s_x[T_][F_];      // 32 KB
    __shared__ float s_h[H_];
    __shared__ float s_gates[G4_];

    // --- load W_hh row g into registers (128 VGPR) ---
    float wh[H_];
    #pragma unroll
    for (int k = 0; k < H_; k += 4) {
        const float4 v = *reinterpret_cast<const float4*>(&W_hh[(size_t)g * H_ + k]);
        wh[k] = v.x; wh[k+1] = v.y; wh[k+2] = v.z; wh[k+3] = v.w;
    }
    float wi[F_];
    #pragma unroll
    for (int f = 0; f < F_; f += 4) {
        const float4 v = *reinterpret_cast<const float4*>(&W_ih[(size_t)g * F_ + f]);
        wi[f] = v.x; wi[f+1] = v.y; wi[f+2] = v.z; wi[f+3] = v.w;
    }
    const float bias = b_ih[g] + b_hh[g];

    // --- stage this sequence's x into LDS ---
    // x[b, t, n, f] at (((b*T + t)*N + n)*F + f)
    for (int idx = threadIdx.x; idx < T_ * F_; idx += 512) {
        const int t = idx >> 4;
        const int f = idx & 15;
        s_x[t][f] = x[(((size_t)b * T_ + t) * N_ + n) * F_ + f];
    }
    if (g < H_) s_h[g] = 0.0f;
    float c = 0.0f;                    // valid for threads g < 128
    __syncthreads();

    for (int t = 0; t < T_; ++t) {
        // gate preactivation: bias + W_ih row . x[t] + W_hh row . h
        float a0 = 0.f, a1 = 0.f, a2 = 0.f, a3 = 0.f;
        #pragma unroll
        for (int f = 0; f < F_; f += 4) {
            a0 += wi[f+0] * s_x[t][f+0];
            a1 += wi[f+1] * s_x[t][f+1];
            a2 += wi[f+2] * s_x[t][f+2];
            a3 += wi[f+3] * s_x[t][f+3];
        }
        #pragma unroll
        for (int k = 0; k < H_; k += 4) {
            a0 += wh[k+0] * s_h[k+0];
            a1 += wh[k+1] * s_h[k+1];
            a2 += wh[k+2] * s_h[k+2];
            a3 += wh[k+3] * s_h[k+3];
        }
        const float acc = bias + ((a0 + a1) + (a2 + a3));

        // activation: gates order (i, f, g, o); g-slice [256,384) is tanh
        float av;
        if (g >= 256 && g < 384) {
            // robust tanh: sign * (1 - e^{-2|x|}) / (1 + e^{-2|x|})
            const float ax = fabsf(acc);
            const float e  = __expf(-2.0f * ax);
            const float th = (1.0f - e) / (1.0f + e);
            av = (acc >= 0.0f) ? th : -th;
        } else {
            av = 1.0f / (1.0f + __expf(-acc));
        }
        s_gates[g] = av;
        __syncthreads();

        if (g < H_) {
            const float ig = s_gates[g];
            const float fg = s_gates[g + 128];
            const float gg = s_gates[g + 256];
            const float og = s_gates[g + 384];
            c = fg * c + ig * gg;
            const float ax = fabsf(c);
            const float e  = __expf(-2.0f * ax);
            float th = (1.0f - e) / (1.0f + e);
            th = (c >= 0.0f) ? th : -th;
            s_h[g] = og * th;
        }
        __syncthreads();
    }

    if (g < H_) h_out[(size_t)m * H_ + g] = s_h[g];
}

// ---------------------------------------------------------------------------
// Head kernel: one block per batch element b. GCN + linears + sigmoid.
// ---------------------------------------------------------------------------
__global__ __launch_bounds__(256) void head_kernel(
    const float* __restrict__ adj,     // [N, N]
    const float* __restrict__ W_gcn,   // [64, 128]
    const float* __restrict__ b_gcn,   // [64]
    const float* __restrict__ W_out,   // [1, 64]
    const float* __restrict__ b_out,   // [1]
    const float* __restrict__ W_lin1,  // [28, 14]
    const float* __restrict__ b_lin1,  // [28]
    const float* __restrict__ h_in,    // [B*N, H]
    float* __restrict__ out)           // [B, 28]
{
    const int b   = blockIdx.x;
    const int tid = threadIdx.x;

    __shared__ float s_A[N_][N_];
    __shared__ float s_d[N_];
    __shared__ float s_h[N_][H_];
    __shared__ float s_xg[N_][H_];
    __shared__ float s_g1[N_][64];
    __shared__ float s_s[N_];

    // load lstm_out for this batch
    for (int idx = tid; idx < N_ * H_; idx += 256)
        s_h[idx >> 7][idx & 127] = h_in[(size_t)b * N_ * H_ + idx];

    // degree of A_hat = adj + I (row sums)
    if (tid < N_) {
        float sum = 0.0f;
        for (int j = 0; j < N_; ++j)
            sum += adj[tid * N_ + j] + (tid == j ? 1.0f : 0.0f);
        s_d[tid] = rsqrtf(sum);
    }
    __syncthreads();

    if (tid < N_ * N_) {
        const int i = tid / N_, j = tid % N_;
        const float a = adj[i * N_ + j] + (i == j ? 1.0f : 0.0f);
        s_A[i][j] = s_d[i] * a * s_d[j];
    }
    __syncthreads();

    // x_gcn = A_norm @ h : [14, 128]
    for (int idx = tid; idx < N_ * H_; idx += 256) {
        const int i = idx >> 7, k = idx & 127;
        float acc = 0.0f;
        #pragma unroll
        for (int j = 0; j < N_; ++j) acc += s_A[i][j] * s_h[j][k];
        s_xg[i][k] = acc;
    }
    __syncthreads();

    // relu(x_gcn @ W_gcn.T + b_gcn) : [14, 64]
    for (int idx = tid; idx < N_ * 64; idx += 256) {
        const int i = idx >> 6, q = idx & 63;
        float a0 = 0.f, a1 = 0.f, a2 = 0.f, a3 = 0.f;
        #pragma unroll
        for (int k = 0; k < H_; k += 4) {
            a0 += s_xg[i][k+0] * W_gcn[q * H_ + k+0];
            a1 += s_xg[i][k+1] * W_gcn[q * H_ + k+1];
            a2 += s_xg[i][k+2] * W_gcn[q * H_ + k+2];
            a3 += s_xg[i][k+3] * W_gcn[q * H_ + k+3];
        }
        const float acc = b_gcn[q] + ((a0 + a1) + (a2 + a3));
        s_g1[i][q] = fmaxf(acc, 0.0f);
    }
    __syncthreads();

    // (g1 @ W_out.T + b_out) : [14]
    if (tid < N_) {
        float acc = b_out[0];
        #pragma unroll
        for (int q = 0; q < 64; ++q) acc += s_g1[tid][q] * W_out[q];
        s_s[tid] = acc;
    }
    __syncthreads();

    // sigmoid(s @ W_lin1.T + b_lin1) : [28]
    if (tid < 28) {
        float acc = b_lin1[tid];
        #pragma unroll
        for (int i = 0; i < N_; ++i) acc += s_s[i] * W_lin1[tid * N_ + i];
        out[b * 28 + tid] = 1.0f / (1.0f + __expf(-acc));
    }
}

extern "C" void kernel_launch(void* const* d_in, const int* in_sizes, int n_in,
                              void* d_out, int out_size, void* d_ws, size_t ws_size,
                              hipStream_t stream) {
    const float* x      = (const float*)d_in[0];
    const float* adj    = (const float*)d_in[1];
    const float* W_ih   = (const float*)d_in[2];
    const float* W_hh   = (const float*)d_in[3];
    const float* b_ih   = (const float*)d_in[4];
    const float* b_hh   = (const float*)d_in[5];
    const float* W_gcn  = (const float*)d_in[6];
    const float* b_gcn  = (const float*)d_in[7];
    const float* W_out  = (const float*)d_in[8];
    const float* b_out  = (const float*)d_in[9];
    const float* W_lin1 = (const float*)d_in[10];
    const float* b_lin1 = (const float*)d_in[11];
    float* out = (float*)d_out;

    float* h_last = (float*)d_ws;   // [896, 128] fp32 = 458752 B

    lstm_kernel<<<B_ * N_, 512, 0, stream>>>(x, W_ih, W_hh, b_ih, b_hh, h_last);
    head_kernel<<<B_, 256, 0, stream>>>(adj, W_gcn, b_gcn, W_out, b_out,
                                        W_lin1, b_lin1, h_last, out);
}

// Round 2
// 840.016 us; speedup vs baseline: 2.3392x; 2.3392x over previous
//
#include <hip/hip_runtime.h>
#include <hip/hip_bf16.h>

#define B_   64
#define T_   512
#define N_   14
#define F_   16
#define H_   128
#define G4_  512   // 4*H
#define TCH  32    // timesteps staged per LDS chunk
#define MBLK 16    // sequences per block

typedef __attribute__((ext_vector_type(8))) short bfrag;   // 8 bf16 (4 VGPR)
typedef __attribute__((ext_vector_type(4))) float facc;    // fp32 accumulator

__device__ __forceinline__ short f2bf(float f) {
    unsigned u = __builtin_bit_cast(unsigned, f);
    return (short)((u + 0x7FFFu + ((u >> 16) & 1u)) >> 16);
}
__device__ __forceinline__ float bf2f(unsigned short s) {
    return __builtin_bit_cast(float, (unsigned)s << 16);
}
__device__ __forceinline__ float sigm(float v) {
    float e = __expf(-v);
    return __fdividef(1.0f, 1.0f + e);
}
__device__ __forceinline__ float tanh_fast(float v) {
    float e = __expf(-2.0f * fabsf(v));
    float t = __fdividef(1.0f - e, 1.0f + e);
    return (v >= 0.0f) ? t : -t;
}

// ---------------------------------------------------------------------------
// Prep: convert weights to bf16 (W_ih zero-padded K=16->32), fuse biases.
// ---------------------------------------------------------------------------
__global__ void prep_kernel(const float* __restrict__ W_ih, const float* __restrict__ W_hh,
                            const float* __restrict__ b_ih, const float* __restrict__ b_hh,
                            short* __restrict__ whh_bf, short* __restrict__ wih_bf,
                            float* __restrict__ bias) {
    int i = blockIdx.x * blockDim.x + threadIdx.x;      // 0 .. 65535
    if (i < G4_ * H_) whh_bf[i] = f2bf(W_hh[i]);
    if (i < G4_ * 32) {
        int n = i >> 5, k = i & 31;
        wih_bf[i] = (k < F_) ? f2bf(W_ih[n * F_ + k]) : (short)0;
    }
    if (i < G4_) bias[i] = b_ih[i] + b_hh[i];
}

// ---------------------------------------------------------------------------
// LSTM via MFMA: 56 blocks x 512 thr. Block owns 16 sequences; wave w owns
// h-columns [16w,16w+16) across all 4 gate sections -> in-register c/h update.
// ---------------------------------------------------------------------------
__global__ __launch_bounds__(512, 1) void lstm_mfma_kernel(
    const float* __restrict__ x,         // [B, T, N, F] fp32
    const short* __restrict__ whh_bf,    // [512][128] bf16
    const short* __restrict__ wih_bf,    // [512][32]  bf16 (k>=16 zero)
    const float* __restrict__ bias,      // [512] fp32
    unsigned short* __restrict__ h_out)  // [896][128] bf16
{
    const int m0  = blockIdx.x * MBLK;   // global sequence base
    const int tid = threadIdx.x;
    const int w   = tid >> 6;            // wave 0..7
    const int l   = tid & 63;
    const int lr  = l & 15;              // tile row/col index
    const int lk  = l >> 4;              // k-block 0..3
    const int hcol = w * 16 + lr;        // this lane's h-column

    __shared__ __align__(16) short sx[TCH * 16 * 32];  // 32 KB, swizzled
    __shared__ __align__(16) short sh[2][16 * 128];    // 2 x 4 KB, swizzled

    // ---- load B fragments into registers ----
    bfrag Bh[4][4];                      // [gate q][kstep]
    bfrag Bx[4];
    facc  bsp[4];
    #pragma unroll
    for (int q = 0; q < 4; ++q) {
        const int n = q * H_ + hcol;     // gate row in [0,512)
        #pragma unroll
        for (int ks = 0; ks < 4; ++ks) {
            const int kbase = lk * 8 + ks * 32;
            Bh[q][ks] = *(const bfrag*)(whh_bf + n * H_ + kbase);
        }
        Bx[q] = *(const bfrag*)(wih_bf + n * 32 + lk * 8);
        const float b = bias[n];
        bsp[q] = (facc){b, b, b, b};
    }

    float cc[4] = {0.f, 0.f, 0.f, 0.f};

    // swizzled loop-invariant LDS offsets
    const int swz   = (lr & 7) << 4;
    const int xoff  = ((lr * 64 + lk * 16) ^ swz);     // + tl*1024 per step
    int hoff[4];
    #pragma unroll
    for (int ks = 0; ks < 4; ++ks)
        hoff[ks] = (lr * 256 + lk * 16 + ks * 64) ^ swz;

    // ---- zero LDS (sx zero-pad region persists; sh[0] is h=0 init) ----
    for (int i = tid; i < (TCH * 16 * 32) / 2; i += 512) ((int*)sx)[i] = 0;
    for (int i = tid; i < (2 * 16 * 128) / 2; i += 512) ((int*)sh)[i] = 0;
    __syncthreads();

    for (int t0 = 0; t0 < T_; t0 += TCH) {
        // ---- stage x chunk (only k<16 slots; pad region already zero) ----
        for (int s = tid; s < TCH * 16 * 2; s += 512) {
            const int tl  = s >> 5;
            const int rem = s & 31;
            const int seq = rem >> 1;
            const int kb  = rem & 1;
            const int sg  = m0 + seq;
            const int bb  = sg / N_;
            const int nn  = sg % N_;
            const float* xp = x + ((((size_t)bb * T_ + (t0 + tl)) * N_ + nn) * F_ + kb * 8);
            const float4 v0 = *(const float4*)xp;
            const float4 v1 = *(const float4*)(xp + 4);
            bfrag o;
            o[0] = f2bf(v0.x); o[1] = f2bf(v0.y); o[2] = f2bf(v0.z); o[3] = f2bf(v0.w);
            o[4] = f2bf(v1.x); o[5] = f2bf(v1.y); o[6] = f2bf(v1.z); o[7] = f2bf(v1.w);
            const int byte = ((tl * 16 + seq) * 64 + kb * 16) ^ ((seq & 7) << 4);
            *(bfrag*)((char*)sx + byte) = o;
        }
        __syncthreads();

        for (int tl = 0; tl < TCH; ++tl) {
            const int t   = t0 + tl;
            const int cur = t & 1, nxt = cur ^ 1;
            const char* shc = (const char*)sh[cur];

            // A fragments
            const bfrag Ax = *(const bfrag*)((const char*)sx + (tl * 1024 + xoff));
            bfrag Ah[4];
            #pragma unroll
            for (int ks = 0; ks < 4; ++ks)
                Ah[ks] = *(const bfrag*)(shc + hoff[ks]);

            // gates = bias + x W_ih^T + h W_hh^T  (fp32 accum)
            facc acc[4];
            #pragma unroll
            for (int q = 0; q < 4; ++q)
                acc[q] = __builtin_amdgcn_mfma_f32_16x16x32_bf16(Ax, Bx[q], bsp[q], 0, 0, 0);
            #pragma unroll
            for (int ks = 0; ks < 4; ++ks)
                #pragma unroll
                for (int q = 0; q < 4; ++q)
                    acc[q] = __builtin_amdgcn_mfma_f32_16x16x32_bf16(Ah[ks], Bh[q][ks], acc[q], 0, 0, 0);

            // epilogue: per lane 4 rows (seq = lk*4+r) at column hcol
            char* shn = (char*)sh[nxt];
            #pragma unroll
            for (int r = 0; r < 4; ++r) {
                const float gi = sigm(acc[0][r]);
                const float gf = sigm(acc[1][r]);
                const float gg = tanh_fast(acc[2][r]);
                const float go = sigm(acc[3][r]);
                cc[r] = gf * cc[r] + gi * gg;
                const float hv = go * tanh_fast(cc[r]);
                const int m = lk * 4 + r;
                const int byte = (m * 256 + hcol * 2) ^ ((m & 7) << 4);
                *(short*)(shn + byte) = f2bf(hv);
            }
            __syncthreads();
        }
    }

    // final h is in sh[0] (T even); write out bf16
    for (int i = tid; i < MBLK * H_; i += 512) {
        const int m = i >> 7, col = i & 127;
        const int byte = (m * 256 + col * 2) ^ ((m & 7) << 4);
        h_out[(size_t)(m0 + m) * H_ + col] = *(unsigned short*)((char*)sh[0] + byte);
    }
}

// ---------------------------------------------------------------------------
// Head kernel: one block per batch element b. GCN + linears + sigmoid.
// ---------------------------------------------------------------------------
__global__ __launch_bounds__(256) void head_kernel(
    const float* __restrict__ adj,
    const float* __restrict__ W_gcn, const float* __restrict__ b_gcn,
    const float* __restrict__ W_out, const float* __restrict__ b_out,
    const float* __restrict__ W_lin1, const float* __restrict__ b_lin1,
    const unsigned short* __restrict__ h_in,   // [896][128] bf16
    float* __restrict__ out)                   // [B, 28]
{
    const int b   = blockIdx.x;
    const int tid = threadIdx.x;

    __shared__ float s_A[N_][N_];
    __shared__ float s_d[N_];
    __shared__ float s_h[N_][H_];
    __shared__ float s_xg[N_][H_];
    __shared__ float s_g1[N_][64];
    __shared__ float s_s[N_];

    for (int idx = tid; idx < N_ * H_; idx += 256)
        s_h[idx >> 7][idx & 127] = bf2f(h_in[(size_t)b * N_ * H_ + idx]);

    if (tid < N_) {
        float sum = 0.0f;
        for (int j = 0; j < N_; ++j)
            sum += adj[tid * N_ + j] + (tid == j ? 1.0f : 0.0f);
        s_d[tid] = rsqrtf(sum);
    }
    __syncthreads();

    if (tid < N_ * N_) {
        const int i = tid / N_, j = tid % N_;
        const float a = adj[i * N_ + j] + (i == j ? 1.0f : 0.0f);
        s_A[i][j] = s_d[i] * a * s_d[j];
    }
    __syncthreads();

    for (int idx = tid; idx < N_ * H_; idx += 256) {
        const int i = idx >> 7, k = idx & 127;
        float acc = 0.0f;
        #pragma unroll
        for (int j = 0; j < N_; ++j) acc += s_A[i][j] * s_h[j][k];
        s_xg[i][k] = acc;
    }
    __syncthreads();

    for (int idx = tid; idx < N_ * 64; idx += 256) {
        const int i = idx >> 6, q = idx & 63;
        float a0 = 0.f, a1 = 0.f, a2 = 0.f, a3 = 0.f;
        #pragma unroll
        for (int k = 0; k < H_; k += 4) {
            a0 += s_xg[i][k+0] * W_gcn[q * H_ + k+0];
            a1 += s_xg[i][k+1] * W_gcn[q * H_ + k+1];
            a2 += s_xg[i][k+2] * W_gcn[q * H_ + k+2];
            a3 += s_xg[i][k+3] * W_gcn[q * H_ + k+3];
        }
        const float acc = b_gcn[q] + ((a0 + a1) + (a2 + a3));
        s_g1[i][q] = fmaxf(acc, 0.0f);
    }
    __syncthreads();

    if (tid < N_) {
        float acc = b_out[0];
        #pragma unroll
        for (int q = 0; q < 64; ++q) acc += s_g1[tid][q] * W_out[q];
        s_s[tid] = acc;
    }
    __syncthreads();

    if (tid < 28) {
        float acc = b_lin1[tid];
        #pragma unroll
        for (int i = 0; i < N_; ++i) acc += s_s[i] * W_lin1[tid * N_ + i];
        out[b * 28 + tid] = 1.0f / (1.0f + __expf(-acc));
    }
}

extern "C" void kernel_launch(void* const* d_in, const int* in_sizes, int n_in,
                              void* d_out, int out_size, void* d_ws, size_t ws_size,
                              hipStream_t stream) {
    const float* x      = (const float*)d_in[0];
    const float* adj    = (const float*)d_in[1];
    const float* W_ih   = (const float*)d_in[2];
    const float* W_hh   = (const float*)d_in[3];
    const float* b_ih   = (const float*)d_in[4];
    const float* b_hh   = (const float*)d_in[5];
    const float* W_gcn  = (const float*)d_in[6];
    const float* b_gcn  = (const float*)d_in[7];
    const float* W_out  = (const float*)d_in[8];
    const float* b_out  = (const float*)d_in[9];
    const float* W_lin1 = (const float*)d_in[10];
    const float* b_lin1 = (const float*)d_in[11];
    float* out = (float*)d_out;

    // workspace layout (bytes): total 395264 < 458752 proven available
    char* ws = (char*)d_ws;
    short*          whh_bf = (short*)(ws);                    // 512*128*2 = 131072
    short*          wih_bf = (short*)(ws + 131072);           // 512*32*2  =  32768
    float*          bias   = (float*)(ws + 163840);           // 512*4     =   2048
    unsigned short* h_last = (unsigned short*)(ws + 165888);  // 896*128*2 = 229376

    prep_kernel<<<128, 512, 0, stream>>>(W_ih, W_hh, b_ih, b_hh, whh_bf, wih_bf, bias);
    lstm_mfma_kernel<<<(B_ * N_) / MBLK, 512, 0, stream>>>(x, whh_bf, wih_bf, bias, h_last);
    head_kernel<<<B_, 256, 0, stream>>>(adj, W_gcn, b_gcn, W_out, b_out,
                                        W_lin1, b_lin1, h_last, out);
}

// Round 3
// 502.858 us; speedup vs baseline: 3.9076x; 1.6705x over previous
//
#include <hip/hip_runtime.h>
#include <hip/hip_bf16.h>

#define B_   64
#define T_   512
#define N_   14
#define F_   16
#define H_   128
#define G4_  512   // 4*H
#define TCH  32    // timesteps staged per LDS chunk
#define MBLK 16    // sequences per block

typedef __attribute__((ext_vector_type(8))) short bfrag;   // 8 bf16 (4 VGPR)
typedef __attribute__((ext_vector_type(4))) float facc;    // fp32 accumulator

__device__ __forceinline__ short f2bf(float f) {
    unsigned u = __builtin_bit_cast(unsigned, f);
    return (short)((u + 0x7FFFu + ((u >> 16) & 1u)) >> 16);
}
__device__ __forceinline__ float bf2f(unsigned short s) {
    return __builtin_bit_cast(float, (unsigned)s << 16);
}
__device__ __forceinline__ float frcp(float v) {
    return __builtin_amdgcn_rcpf(v);
}

// ---------------------------------------------------------------------------
// Prep: convert weights to bf16 (W_ih zero-padded K=16->32), fuse biases.
// ---------------------------------------------------------------------------
__global__ void prep_kernel(const float* __restrict__ W_ih, const float* __restrict__ W_hh,
                            const float* __restrict__ b_ih, const float* __restrict__ b_hh,
                            short* __restrict__ whh_bf, short* __restrict__ wih_bf,
                            float* __restrict__ bias) {
    int i = blockIdx.x * blockDim.x + threadIdx.x;      // 0 .. 65535
    if (i < G4_ * H_) whh_bf[i] = f2bf(W_hh[i]);
    if (i < G4_ * 32) {
        int n = i >> 5, k = i & 31;
        wih_bf[i] = (k < F_) ? f2bf(W_ih[n * F_ + k]) : (short)0;
    }
    if (i < G4_) bias[i] = b_ih[i] + b_hh[i];
}

// ---------------------------------------------------------------------------
// LSTM via MFMA: 56 blocks x 512 thr. Block owns 16 sequences; wave w owns
// h-columns [16w,16w+16) across all 4 gate sections -> in-register c/h update.
// Weight fragments pinned in VGPRs via keep-alive asm (compiler otherwise
// rematerializes them as in-loop global loads -> L2-bound).
// ---------------------------------------------------------------------------
__global__ __launch_bounds__(512, 1) void lstm_mfma_kernel(
    const float* __restrict__ x,         // [B, T, N, F] fp32
    const short* __restrict__ whh_bf,    // [512][128] bf16
    const short* __restrict__ wih_bf,    // [512][32]  bf16 (k>=16 zero)
    const float* __restrict__ bias,      // [512] fp32
    unsigned short* __restrict__ h_out)  // [896][128] bf16
{
    const int m0  = blockIdx.x * MBLK;   // global sequence base
    const int tid = threadIdx.x;
    const int w   = tid >> 6;            // wave 0..7
    const int l   = tid & 63;
    const int lr  = l & 15;              // tile row/col index
    const int lk  = l >> 4;              // k-block 0..3
    const int hcol = w * 16 + lr;        // this lane's h-column

    __shared__ __align__(16) short sx[TCH * 16 * 32];  // 32 KB, swizzled
    __shared__ __align__(16) short sh[2][16 * 128];    // 2 x 4 KB, swizzled

    // ---- load B fragments into registers (once) ----
    bfrag Bh[4][4];                      // [gate q][kstep]
    bfrag Bx[4];
    facc  bsp[4];
    #pragma unroll
    for (int q = 0; q < 4; ++q) {
        const int n = q * H_ + hcol;     // gate row in [0,512)
        #pragma unroll
        for (int ks = 0; ks < 4; ++ks) {
            const int kbase = lk * 8 + ks * 32;
            Bh[q][ks] = *(const bfrag*)(whh_bf + n * H_ + kbase);
        }
        Bx[q] = *(const bfrag*)(wih_bf + n * 32 + lk * 8);
        const float b = bias[n];
        bsp[q] = (facc){b, b, b, b};
    }
    // Pin fragments as live registers: forbid rematerialization/sinking.
    #pragma unroll
    for (int q = 0; q < 4; ++q) {
        asm volatile("" : "+v"(Bx[q]));
        asm volatile("" : "+v"(bsp[q]));
        #pragma unroll
        for (int ks = 0; ks < 4; ++ks)
            asm volatile("" : "+v"(Bh[q][ks]));
    }

    float cc[4] = {0.f, 0.f, 0.f, 0.f};

    // swizzled loop-invariant LDS offsets
    const int swz   = (lr & 7) << 4;
    const int xoff  = ((lr * 64 + lk * 16) ^ swz);     // + tl*1024 per step
    int hoff[4];
    #pragma unroll
    for (int ks = 0; ks < 4; ++ks)
        hoff[ks] = (lr * 256 + lk * 16 + ks * 64) ^ swz;

    // staging: each thread stages 2 bfrags per chunk; hoist address math
    const int tl1 = tid >> 5;            // 0..15
    const int rem = tid & 31;
    const int seq = rem >> 1;
    const int kb  = rem & 1;
    const int sg  = m0 + seq;
    const int bb  = sg / N_;
    const int nn  = sg % N_;
    const float* xp = x + ((((size_t)bb * T_ + tl1) * N_ + nn) * F_ + kb * 8);
    const int byte1 = ((tl1 * 16 + seq) * 64 + kb * 16) ^ ((seq & 7) << 4);
    const int byte2 = byte1 + 16 * 1024;           // tl + 16
    const int xstep2 = 16 * N_ * F_;               // +16 timesteps (floats)

    // ---- zero LDS (sx zero-pad region persists; sh[0] is h=0 init) ----
    for (int i = tid; i < (TCH * 16 * 32) / 2; i += 512) ((int*)sx)[i] = 0;
    for (int i = tid; i < (2 * 16 * 128) / 2; i += 512) ((int*)sh)[i] = 0;
    __syncthreads();

    for (int t0 = 0; t0 < T_; t0 += TCH) {
        // ---- stage x chunk (k<16 slots only; pad region stays zero) ----
        {
            const float4 v0 = *(const float4*)(xp);
            const float4 v1 = *(const float4*)(xp + 4);
            const float4 v2 = *(const float4*)(xp + xstep2);
            const float4 v3 = *(const float4*)(xp + xstep2 + 4);
            xp += TCH * N_ * F_;
            bfrag o1, o2;
            o1[0] = f2bf(v0.x); o1[1] = f2bf(v0.y); o1[2] = f2bf(v0.z); o1[3] = f2bf(v0.w);
            o1[4] = f2bf(v1.x); o1[5] = f2bf(v1.y); o1[6] = f2bf(v1.z); o1[7] = f2bf(v1.w);
            o2[0] = f2bf(v2.x); o2[1] = f2bf(v2.y); o2[2] = f2bf(v2.z); o2[3] = f2bf(v2.w);
            o2[4] = f2bf(v3.x); o2[5] = f2bf(v3.y); o2[6] = f2bf(v3.z); o2[7] = f2bf(v3.w);
            *(bfrag*)((char*)sx + byte1) = o1;
            *(bfrag*)((char*)sx + byte2) = o2;
        }
        __syncthreads();

        for (int tl = 0; tl < TCH; ++tl) {
            const int t   = t0 + tl;
            const int cur = t & 1, nxt = cur ^ 1;
            const char* shc = (const char*)sh[cur];

            // A fragments
            const bfrag Ax = *(const bfrag*)((const char*)sx + (tl * 1024 + xoff));
            bfrag Ah[4];
            #pragma unroll
            for (int ks = 0; ks < 4; ++ks)
                Ah[ks] = *(const bfrag*)(shc + hoff[ks]);

            // gates = bias + x W_ih^T + h W_hh^T (two partial acc chains: 3+2)
            facc acc[4], ac2[4];
            #pragma unroll
            for (int q = 0; q < 4; ++q)
                acc[q] = __builtin_amdgcn_mfma_f32_16x16x32_bf16(Ax, Bx[q], bsp[q], 0, 0, 0);
            #pragma unroll
            for (int q = 0; q < 4; ++q)
                acc[q] = __builtin_amdgcn_mfma_f32_16x16x32_bf16(Ah[0], Bh[q][0], acc[q], 0, 0, 0);
            #pragma unroll
            for (int q = 0; q < 4; ++q)
                ac2[q] = __builtin_amdgcn_mfma_f32_16x16x32_bf16(Ah[1], Bh[q][1],
                                                                 (facc){0.f,0.f,0.f,0.f}, 0, 0, 0);
            #pragma unroll
            for (int q = 0; q < 4; ++q)
                acc[q] = __builtin_amdgcn_mfma_f32_16x16x32_bf16(Ah[2], Bh[q][2], acc[q], 0, 0, 0);
            #pragma unroll
            for (int q = 0; q < 4; ++q)
                ac2[q] = __builtin_amdgcn_mfma_f32_16x16x32_bf16(Ah[3], Bh[q][3], ac2[q], 0, 0, 0);

            // epilogue: per lane 4 rows (seq = lk*4+r) at column hcol
            // sigma(i)*tanh(g) = (1-eg)/((1+ea)(1+eg)) * sign(g)  [1 rcp]
            // sigma(o)*tanh(c) = (1-ec)/((1+eo)(1+ec)) * sign(c)  [1 rcp]
            char* shn = (char*)sh[nxt];
            #pragma unroll
            for (int r = 0; r < 4; ++r) {
                const float zi = acc[0][r] + ac2[0][r];
                const float zf = acc[1][r] + ac2[1][r];
                const float zg = acc[2][r] + ac2[2][r];
                const float zo = acc[3][r] + ac2[3][r];
                const float ea = __expf(-zi);
                const float ef = __expf(-zf);
                const float eo = __expf(-zo);
                const float eg = __expf(-2.0f * fabsf(zg));
                const float ig = __builtin_copysignf(
                    (1.0f - eg) * frcp((1.0f + ea) * (1.0f + eg)), zg);
                const float sf = frcp(1.0f + ef);
                cc[r] = sf * cc[r] + ig;
                const float ec = __expf(-2.0f * fabsf(cc[r]));
                const float hv = __builtin_copysignf(
                    (1.0f - ec) * frcp((1.0f + eo) * (1.0f + ec)), cc[r]);
                const int m = lk * 4 + r;
                const int byte = (m * 256 + hcol * 2) ^ ((m & 7) << 4);
                *(short*)(shn + byte) = f2bf(hv);
            }
            __syncthreads();
        }
    }

    // final h is in sh[0] (T even); write out bf16
    for (int i = tid; i < MBLK * H_; i += 512) {
        const int m = i >> 7, col = i & 127;
        const int byte = (m * 256 + col * 2) ^ ((m & 7) << 4);
        h_out[(size_t)(m0 + m) * H_ + col] = *(unsigned short*)((char*)sh[0] + byte);
    }
}

// ---------------------------------------------------------------------------
// Head kernel: one block per batch element b. GCN + linears + sigmoid.
// ---------------------------------------------------------------------------
__global__ __launch_bounds__(256) void head_kernel(
    const float* __restrict__ adj,
    const float* __restrict__ W_gcn, const float* __restrict__ b_gcn,
    const float* __restrict__ W_out, const float* __restrict__ b_out,
    const float* __restrict__ W_lin1, const float* __restrict__ b_lin1,
    const unsigned short* __restrict__ h_in,   // [896][128] bf16
    float* __restrict__ out)                   // [B, 28]
{
    const int b   = blockIdx.x;
    const int tid = threadIdx.x;

    __shared__ float s_A[N_][N_];
    __shared__ float s_d[N_];
    __shared__ float s_h[N_][H_];
    __shared__ float s_xg[N_][H_];
    __shared__ float s_g1[N_][64];
    __shared__ float s_s[N_];

    for (int idx = tid; idx < N_ * H_; idx += 256)
        s_h[idx >> 7][idx & 127] = bf2f(h_in[(size_t)b * N_ * H_ + idx]);

    if (tid < N_) {
        float sum = 0.0f;
        for (int j = 0; j < N_; ++j)
            sum += adj[tid * N_ + j] + (tid == j ? 1.0f : 0.0f);
        s_d[tid] = rsqrtf(sum);
    }
    __syncthreads();

    if (tid < N_ * N_) {
        const int i = tid / N_, j = tid % N_;
        const float a = adj[i * N_ + j] + (i == j ? 1.0f : 0.0f);
        s_A[i][j] = s_d[i] * a * s_d[j];
    }
    __syncthreads();

    for (int idx = tid; idx < N_ * H_; idx += 256) {
        const int i = idx >> 7, k = idx & 127;
        float acc = 0.0f;
        #pragma unroll
        for (int j = 0; j < N_; ++j) acc += s_A[i][j] * s_h[j][k];
        s_xg[i][k] = acc;
    }
    __syncthreads();

    for (int idx = tid; idx < N_ * 64; idx += 256) {
        const int i = idx >> 6, q = idx & 63;
        float a0 = 0.f, a1 = 0.f, a2 = 0.f, a3 = 0.f;
        #pragma unroll
        for (int k = 0; k < H_; k += 4) {
            a0 += s_xg[i][k+0] * W_gcn[q * H_ + k+0];
            a1 += s_xg[i][k+1] * W_gcn[q * H_ + k+1];
            a2 += s_xg[i][k+2] * W_gcn[q * H_ + k+2];
            a3 += s_xg[i][k+3] * W_gcn[q * H_ + k+3];
        }
        const float acc = b_gcn[q] + ((a0 + a1) + (a2 + a3));
        s_g1[i][q] = fmaxf(acc, 0.0f);
    }
    __syncthreads();

    if (tid < N_) {
        float acc = b_out[0];
        #pragma unroll
        for (int q = 0; q < 64; ++q) acc += s_g1[tid][q] * W_out[q];
        s_s[tid] = acc;
    }
    __syncthreads();

    if (tid < 28) {
        float acc = b_lin1[tid];
        #pragma unroll
        for (int i = 0; i < N_; ++i) acc += s_s[i] * W_lin1[tid * N_ + i];
        out[b * 28 + tid] = 1.0f / (1.0f + __expf(-acc));
    }
}

extern "C" void kernel_launch(void* const* d_in, const int* in_sizes, int n_in,
                              void* d_out, int out_size, void* d_ws, size_t ws_size,
                              hipStream_t stream) {
    const float* x      = (const float*)d_in[0];
    const float* adj    = (const float*)d_in[1];
    const float* W_ih   = (const float*)d_in[2];
    const float* W_hh   = (const float*)d_in[3];
    const float* b_ih   = (const float*)d_in[4];
    const float* b_hh   = (const float*)d_in[5];
    const float* W_gcn  = (const float*)d_in[6];
    const float* b_gcn  = (const float*)d_in[7];
    const float* W_out  = (const float*)d_in[8];
    const float* b_out  = (const float*)d_in[9];
    const float* W_lin1 = (const float*)d_in[10];
    const float* b_lin1 = (const float*)d_in[11];
    float* out = (float*)d_out;

    // workspace layout (bytes): total 395264
    char* ws = (char*)d_ws;
    short*          whh_bf = (short*)(ws);                    // 512*128*2 = 131072
    short*          wih_bf = (short*)(ws + 131072);           // 512*32*2  =  32768
    float*          bias   = (float*)(ws + 163840);           // 512*4     =   2048
    unsigned short* h_last = (unsigned short*)(ws + 165888);  // 896*128*2 = 229376

    prep_kernel<<<128, 512, 0, stream>>>(W_ih, W_hh, b_ih, b_hh, whh_bf, wih_bf, bias);
    lstm_mfma_kernel<<<(B_ * N_) / MBLK, 512, 0, stream>>>(x, whh_bf, wih_bf, bias, h_last);
    head_kernel<<<B_, 256, 0, stream>>>(adj, W_gcn, b_gcn, W_out, b_out,
                                        W_lin1, b_lin1, h_last, out);
}

// Round 4
// 429.945 us; speedup vs baseline: 4.5702x; 1.1696x over previous
//
#include <hip/hip_runtime.h>
#include <hip/hip_bf16.h>

#define B_   64
#define T_   512
#define N_   14
#define F_   16
#define H_   128
#define G4_  512   // 4*H
#define TCH  32    // timesteps staged per LDS chunk
#define MBLK 16    // sequences per block

typedef __attribute__((ext_vector_type(8))) short bfrag;   // 8 bf16 (4 VGPR)
typedef __attribute__((ext_vector_type(4))) float facc;    // fp32 accumulator

__device__ __forceinline__ short f2bf(float f) {
    unsigned u = __builtin_bit_cast(unsigned, f);
    return (short)((u + 0x7FFFu + ((u >> 16) & 1u)) >> 16);
}
__device__ __forceinline__ float bf2f(unsigned short s) {
    return __builtin_bit_cast(float, (unsigned)s << 16);
}
__device__ __forceinline__ unsigned cvt_pk_bf16(float a, float b) {
    unsigned r;
    asm("v_cvt_pk_bf16_f32 %0, %1, %2" : "=v"(r) : "v"(a), "v"(b));
    return r;
}

// ---------------------------------------------------------------------------
// Prep: convert weights to bf16 (W_ih zero-padded K=16->32), fuse biases.
// ---------------------------------------------------------------------------
__global__ void prep_kernel(const float* __restrict__ W_ih, const float* __restrict__ W_hh,
                            const float* __restrict__ b_ih, const float* __restrict__ b_hh,
                            short* __restrict__ whh_bf, short* __restrict__ wih_bf,
                            float* __restrict__ bias) {
    int i = blockIdx.x * blockDim.x + threadIdx.x;      // 0 .. 65535
    if (i < G4_ * H_) whh_bf[i] = f2bf(W_hh[i]);
    if (i < G4_ * 32) {
        int n = i >> 5, k = i & 31;
        wih_bf[i] = (k < F_) ? f2bf(W_ih[n * F_ + k]) : (short)0;
    }
    if (i < G4_) bias[i] = b_ih[i] + b_hh[i];
}

// ---------------------------------------------------------------------------
// One LSTM timestep. RD/WR: byte offsets of read/write h buffers (0 or 4096).
// PREF: prefetch next step's x-contribution (independent of h).
// ---------------------------------------------------------------------------
template<int RD, int WR, bool PREF>
__device__ __forceinline__ void lstm_step(char* shraw, const char* sx_next,
    const bfrag (&Bh)[4][4], const bfrag (&Bx)[4], const facc (&bsp)[4],
    facc (&xacc)[4], float (&cc)[4], const int (&hoff)[4], const int (&stoff)[4])
{
    const bfrag Ah0 = *(const bfrag*)(shraw + RD + hoff[0]);
    const bfrag Ah1 = *(const bfrag*)(shraw + RD + hoff[1]);
    const bfrag Ah2 = *(const bfrag*)(shraw + RD + hoff[2]);
    const bfrag Ah3 = *(const bfrag*)(shraw + RD + hoff[3]);
    bfrag Axn;
    if (PREF) Axn = *(const bfrag*)sx_next;

    // gates = xacc(t) + h W_hh^T : 4 independent q-chains, 4-deep each
    facc acc[4];
#pragma unroll
    for (int q = 0; q < 4; ++q)
        acc[q] = __builtin_amdgcn_mfma_f32_16x16x32_bf16(Ah0, Bh[q][0], xacc[q], 0, 0, 0);
#pragma unroll
    for (int q = 0; q < 4; ++q)
        acc[q] = __builtin_amdgcn_mfma_f32_16x16x32_bf16(Ah1, Bh[q][1], acc[q], 0, 0, 0);
#pragma unroll
    for (int q = 0; q < 4; ++q)
        acc[q] = __builtin_amdgcn_mfma_f32_16x16x32_bf16(Ah2, Bh[q][2], acc[q], 0, 0, 0);
#pragma unroll
    for (int q = 0; q < 4; ++q)
        acc[q] = __builtin_amdgcn_mfma_f32_16x16x32_bf16(Ah3, Bh[q][3], acc[q], 0, 0, 0);

    // next step's x-part (fills matrix pipe during epilogue)
    if (PREF) {
#pragma unroll
        for (int q = 0; q < 4; ++q)
            xacc[q] = __builtin_amdgcn_mfma_f32_16x16x32_bf16(Axn, Bx[q], bsp[q], 0, 0, 0);
    }

    // epilogue: per lane 4 rows (seq = lk*4+r) at column hcol
#pragma unroll
    for (int r = 0; r < 4; ++r) {
        const float zi = acc[0][r], zf = acc[1][r], zg = acc[2][r], zo = acc[3][r];
        const float ea = __expf(-zi);
        const float ef = __expf(-zf);
        const float eo = __expf(-zo);
        const float eg = __expf(-2.0f * fabsf(zg));
        const float ig = __builtin_copysignf(
            (1.0f - eg) * __builtin_amdgcn_rcpf((1.0f + ea) * (1.0f + eg)), zg);
        cc[r] = __builtin_amdgcn_rcpf(1.0f + ef) * cc[r] + ig;
        const float ec = __expf(-2.0f * fabsf(cc[r]));
        const float hv = __builtin_copysignf(
            (1.0f - ec) * __builtin_amdgcn_rcpf((1.0f + eo) * (1.0f + ec)), cc[r]);
        *(short*)(shraw + WR + stoff[r]) = (short)cvt_pk_bf16(hv, hv);
    }
    __syncthreads();
}

// ---------------------------------------------------------------------------
// LSTM via MFMA: 56 blocks x 512 thr. Block owns 16 sequences; wave w owns
// h-columns [16w,16w+16) across all 4 gate sections -> in-register c/h update.
// ---------------------------------------------------------------------------
__global__ __launch_bounds__(512, 1) void lstm_mfma_kernel(
    const float* __restrict__ x,         // [B, T, N, F] fp32
    const short* __restrict__ whh_bf,    // [512][128] bf16
    const short* __restrict__ wih_bf,    // [512][32]  bf16 (k>=16 zero)
    const float* __restrict__ bias,      // [512] fp32
    unsigned short* __restrict__ h_out)  // [896][128] bf16
{
    const int m0  = blockIdx.x * MBLK;   // global sequence base
    const int tid = threadIdx.x;
    const int w   = tid >> 6;            // wave 0..7
    const int l   = tid & 63;
    const int lr  = l & 15;              // tile row/col index
    const int lk  = l >> 4;              // k-block 0..3
    const int hcol = w * 16 + lr;        // this lane's h-column

    __shared__ __align__(16) short sx[TCH * 16 * 32];  // 32 KB, swizzled
    __shared__ __align__(16) short sh[2][16 * 128];    // 2 x 4 KB, swizzled

    // ---- load B fragments into registers (once) ----
    bfrag Bh[4][4];                      // [gate q][kstep]
    bfrag Bx[4];
    facc  bsp[4];
    #pragma unroll
    for (int q = 0; q < 4; ++q) {
        const int n = q * H_ + hcol;     // gate row in [0,512)
        #pragma unroll
        for (int ks = 0; ks < 4; ++ks) {
            const int kbase = lk * 8 + ks * 32;
            Bh[q][ks] = *(const bfrag*)(whh_bf + n * H_ + kbase);
        }
        Bx[q] = *(const bfrag*)(wih_bf + n * 32 + lk * 8);
        const float b = bias[n];
        bsp[q] = (facc){b, b, b, b};
    }
    // Pin fragments as live registers: forbid rematerialization/sinking.
    #pragma unroll
    for (int q = 0; q < 4; ++q) {
        asm volatile("" : "+v"(Bx[q]));
        asm volatile("" : "+v"(bsp[q]));
        #pragma unroll
        for (int ks = 0; ks < 4; ++ks)
            asm volatile("" : "+v"(Bh[q][ks]));
    }

    float cc[4] = {0.f, 0.f, 0.f, 0.f};
    facc  xacc[4];

    // swizzled loop-invariant LDS offsets
    const int swz   = (lr & 7) << 4;
    const int xoff  = ((lr * 64 + lk * 16) ^ swz);     // + tl*1024 per step
    int hoff[4];
    #pragma unroll
    for (int ks = 0; ks < 4; ++ks)
        hoff[ks] = (lr * 256 + lk * 16 + ks * 64) ^ swz;
    int stoff[4];
    #pragma unroll
    for (int r = 0; r < 4; ++r) {
        const int m = lk * 4 + r;
        stoff[r] = (m * 256 + hcol * 2) ^ ((m & 7) << 4);
    }

    // staging: each thread stages 2 bfrags per chunk; hoist address math
    const int tl1 = tid >> 5;            // 0..15
    const int rem = tid & 31;
    const int seq = rem >> 1;
    const int kb  = rem & 1;
    const int sg  = m0 + seq;
    const int bb  = sg / N_;
    const int nn  = sg % N_;
    const float* xp = x + ((((size_t)bb * T_ + tl1) * N_ + nn) * F_ + kb * 8);
    const int byte1 = ((tl1 * 16 + seq) * 64 + kb * 16) ^ ((seq & 7) << 4);
    const int byte2 = byte1 + 16 * 1024;           // tl + 16
    const int xstep2 = 16 * N_ * F_;               // +16 timesteps (floats)

    char* shraw = (char*)&sh[0][0];                // buf0 at +0, buf1 at +4096
    char* sxraw = (char*)sx;
    const char* sxp = sxraw + xoff;

    // ---- zero LDS (sx zero-pad region persists; sh[0] is h=0 init) ----
    for (int i = tid; i < (TCH * 16 * 32) / 2; i += 512) ((int*)sx)[i] = 0;
    for (int i = tid; i < (2 * 16 * 128) / 2; i += 512) ((int*)sh)[i] = 0;
    __syncthreads();

    for (int t0 = 0; t0 < T_; t0 += TCH) {
        // ---- stage x chunk (k<16 slots only; pad region stays zero) ----
        {
            const float4 v0 = *(const float4*)(xp);
            const float4 v1 = *(const float4*)(xp + 4);
            const float4 v2 = *(const float4*)(xp + xstep2);
            const float4 v3 = *(const float4*)(xp + xstep2 + 4);
            xp += TCH * N_ * F_;
            uint4 o1, o2;
            o1.x = cvt_pk_bf16(v0.x, v0.y); o1.y = cvt_pk_bf16(v0.z, v0.w);
            o1.z = cvt_pk_bf16(v1.x, v1.y); o1.w = cvt_pk_bf16(v1.z, v1.w);
            o2.x = cvt_pk_bf16(v2.x, v2.y); o2.y = cvt_pk_bf16(v2.z, v2.w);
            o2.z = cvt_pk_bf16(v3.x, v3.y); o2.w = cvt_pk_bf16(v3.z, v3.w);
            *(uint4*)(sxraw + byte1) = o1;
            *(uint4*)(sxraw + byte2) = o2;
        }
        __syncthreads();

        // preamble: xacc for tl=0 of this chunk
        {
            const bfrag Ax = *(const bfrag*)sxp;
            #pragma unroll
            for (int q = 0; q < 4; ++q)
                xacc[q] = __builtin_amdgcn_mfma_f32_16x16x32_bf16(Ax, Bx[q], bsp[q], 0, 0, 0);
        }

        // 32 timesteps: even reads buf0/writes buf1, odd reads buf1/writes buf0
        #pragma unroll 1
        for (int tl = 0; tl < TCH - 2; tl += 2) {
            lstm_step<0, 4096, true >(shraw, sxp + (tl + 1) * 1024, Bh, Bx, bsp, xacc, cc, hoff, stoff);
            lstm_step<4096, 0, true >(shraw, sxp + (tl + 2) * 1024, Bh, Bx, bsp, xacc, cc, hoff, stoff);
        }
        lstm_step<0, 4096, true >(shraw, sxp + 31 * 1024, Bh, Bx, bsp, xacc, cc, hoff, stoff);
        lstm_step<4096, 0, false>(shraw, nullptr,         Bh, Bx, bsp, xacc, cc, hoff, stoff);
    }

    // final h is in sh[0] (T even); write out bf16
    for (int i = tid; i < MBLK * H_; i += 512) {
        const int m = i >> 7, col = i & 127;
        const int byte = (m * 256 + col * 2) ^ ((m & 7) << 4);
        h_out[(size_t)(m0 + m) * H_ + col] = *(unsigned short*)(shraw + byte);
    }
}

// ---------------------------------------------------------------------------
// Head kernel: one block per batch element b. GCN + linears + sigmoid.
// ---------------------------------------------------------------------------
__global__ __launch_bounds__(256) void head_kernel(
    const float* __restrict__ adj,
    const float* __restrict__ W_gcn, const float* __restrict__ b_gcn,
    const float* __restrict__ W_out, const float* __restrict__ b_out,
    const float* __restrict__ W_lin1, const float* __restrict__ b_lin1,
    const unsigned short* __restrict__ h_in,   // [896][128] bf16
    float* __restrict__ out)                   // [B, 28]
{
    const int b   = blockIdx.x;
    const int tid = threadIdx.x;

    __shared__ float s_A[N_][N_];
    __shared__ float s_d[N_];
    __shared__ float s_h[N_][H_];
    __shared__ float s_xg[N_][H_];
    __shared__ float s_g1[N_][64];
    __shared__ float s_s[N_];

    for (int idx = tid; idx < N_ * H_; idx += 256)
        s_h[idx >> 7][idx & 127] = bf2f(h_in[(size_t)b * N_ * H_ + idx]);

    if (tid < N_) {
        float sum = 0.0f;
        for (int j = 0; j < N_; ++j)
            sum += adj[tid * N_ + j] + (tid == j ? 1.0f : 0.0f);
        s_d[tid] = rsqrtf(sum);
    }
    __syncthreads();

    if (tid < N_ * N_) {
        const int i = tid / N_, j = tid % N_;
        const float a = adj[i * N_ + j] + (i == j ? 1.0f : 0.0f);
        s_A[i][j] = s_d[i] * a * s_d[j];
    }
    __syncthreads();

    for (int idx = tid; idx < N_ * H_; idx += 256) {
        const int i = idx >> 7, k = idx & 127;
        float acc = 0.0f;
        #pragma unroll
        for (int j = 0; j < N_; ++j) acc += s_A[i][j] * s_h[j][k];
        s_xg[i][k] = acc;
    }
    __syncthreads();

    for (int idx = tid; idx < N_ * 64; idx += 256) {
        const int i = idx >> 6, q = idx & 63;
        float a0 = 0.f, a1 = 0.f, a2 = 0.f, a3 = 0.f;
        #pragma unroll
        for (int k = 0; k < H_; k += 4) {
            a0 += s_xg[i][k+0] * W_gcn[q * H_ + k+0];
            a1 += s_xg[i][k+1] * W_gcn[q * H_ + k+1];
            a2 += s_xg[i][k+2] * W_gcn[q * H_ + k+2];
            a3 += s_xg[i][k+3] * W_gcn[q * H_ + k+3];
        }
        const float acc = b_gcn[q] + ((a0 + a1) + (a2 + a3));
        s_g1[i][q] = fmaxf(acc, 0.0f);
    }
    __syncthreads();

    if (tid < N_) {
        float acc = b_out[0];
        #pragma unroll
        for (int q = 0; q < 64; ++q) acc += s_g1[tid][q] * W_out[q];
        s_s[tid] = acc;
    }
    __syncthreads();

    if (tid < 28) {
        float acc = b_lin1[tid];
        #pragma unroll
        for (int i = 0; i < N_; ++i) acc += s_s[i] * W_lin1[tid * N_ + i];
        out[b * 28 + tid] = 1.0f / (1.0f + __expf(-acc));
    }
}

extern "C" void kernel_launch(void* const* d_in, const int* in_sizes, int n_in,
                              void* d_out, int out_size, void* d_ws, size_t ws_size,
                              hipStream_t stream) {
    const float* x      = (const float*)d_in[0];
    const float* adj    = (const float*)d_in[1];
    const float* W_ih   = (const float*)d_in[2];
    const float* W_hh   = (const float*)d_in[3];
    const float* b_ih   = (const float*)d_in[4];
    const float* b_hh   = (const float*)d_in[5];
    const float* W_gcn  = (const float*)d_in[6];
    const float* b_gcn  = (const float*)d_in[7];
    const float* W_out  = (const float*)d_in[8];
    const float* b_out  = (const float*)d_in[9];
    const float* W_lin1 = (const float*)d_in[10];
    const float* b_lin1 = (const float*)d_in[11];
    float* out = (float*)d_out;

    // workspace layout (bytes): total 395264
    char* ws = (char*)d_ws;
    short*          whh_bf = (short*)(ws);                    // 512*128*2 = 131072
    short*          wih_bf = (short*)(ws + 131072);           // 512*32*2  =  32768
    float*          bias   = (float*)(ws + 163840);           // 512*4     =   2048
    unsigned short* h_last = (unsigned short*)(ws + 165888);  // 896*128*2 = 229376

    prep_kernel<<<128, 512, 0, stream>>>(W_ih, W_hh, b_ih, b_hh, whh_bf, wih_bf, bias);
    lstm_mfma_kernel<<<(B_ * N_) / MBLK, 512, 0, stream>>>(x, whh_bf, wih_bf, bias, h_last);
    head_kernel<<<B_, 256, 0, stream>>>(adj, W_gcn, b_gcn, W_out, b_out,
                                        W_lin1, b_lin1, h_last, out);
}

// Round 5
// 411.337 us; speedup vs baseline: 4.7770x; 1.0452x over previous
//
#include <hip/hip_runtime.h>
#include <hip/hip_bf16.h>

#define B_   64
#define T_   512
#define N_   14
#define F_   16
#define H_   128
#define G4_  512   // 4*H
#define TCH  64    // timesteps staged per LDS chunk
#define MBLK 4     // sequences per block
#define NBLK ((B_ * N_) / MBLK)   // 224 blocks

typedef __attribute__((ext_vector_type(8))) short bfrag;   // 8 bf16 (4 VGPR)
typedef __attribute__((ext_vector_type(4))) float facc;    // fp32 accumulator

#define L2E   1.4426950408889634f
#define L2E2  2.8853900817779268f

__device__ __forceinline__ short f2bf(float f) {
    unsigned u = __builtin_bit_cast(unsigned, f);
    return (short)((u + 0x7FFFu + ((u >> 16) & 1u)) >> 16);
}
__device__ __forceinline__ float bf2f(unsigned short s) {
    return __builtin_bit_cast(float, (unsigned)s << 16);
}
__device__ __forceinline__ unsigned cvt_pk_bf16(float a, float b) {
    unsigned r;
    asm("v_cvt_pk_bf16_f32 %0, %1, %2" : "=v"(r) : "v"(a), "v"(b));
    return r;
}

// ---------------------------------------------------------------------------
// Prep: bf16 weights scaled by log2(e) (2*log2(e) for the g-gate section) so
// the epilogue uses native exp2. W_ih zero-padded K=16->32; biases fused+scaled.
// ---------------------------------------------------------------------------
__global__ void prep_kernel(const float* __restrict__ W_ih, const float* __restrict__ W_hh,
                            const float* __restrict__ b_ih, const float* __restrict__ b_hh,
                            short* __restrict__ whh_bf, short* __restrict__ wih_bf,
                            float* __restrict__ bias) {
    int i = blockIdx.x * blockDim.x + threadIdx.x;      // 0 .. 65535
    if (i < G4_ * H_) {
        const int n = i >> 7;
        const float sc = (n >= 256 && n < 384) ? L2E2 : L2E;
        whh_bf[i] = f2bf(W_hh[i] * sc);
    }
    if (i < G4_ * 32) {
        const int n = i >> 5, k = i & 31;
        const float sc = (n >= 256 && n < 384) ? L2E2 : L2E;
        wih_bf[i] = (k < F_) ? f2bf(W_ih[n * F_ + k] * sc) : (short)0;
    }
    if (i < G4_) {
        const float sc = (i >= 256 && i < 384) ? L2E2 : L2E;
        bias[i] = (b_ih[i] + b_hh[i]) * sc;
    }
}

// ---------------------------------------------------------------------------
// One LSTM timestep. RD/WR: byte offsets of read/write h buffers within the
// sh region. PREF: prefetch next step's x-contribution MFMA.
// After the MFMAs, the 4 valid output rows (lanes lk=0, regs 0-3) are spread
// across all 64 lanes via ds_bpermute so every lane runs a 1-row epilogue.
// ---------------------------------------------------------------------------
template<int RD, int WR, bool PREF>
__device__ __forceinline__ void lstm_step(char* shbase, const char* sx_next,
    const bfrag (&Bh)[4][4], const bfrag (&Bx)[4], const facc& zf4,
    facc (&xacc)[4], float& cc, const int (&hoff)[4], int stoff,
    int lrsrc, bool b0, bool b1, const float (&bias4)[4])
{
    const bfrag Ah0 = *(const bfrag*)(shbase + RD + hoff[0]);
    const bfrag Ah1 = *(const bfrag*)(shbase + RD + hoff[1]);
    const bfrag Ah2 = *(const bfrag*)(shbase + RD + hoff[2]);
    const bfrag Ah3 = *(const bfrag*)(shbase + RD + hoff[3]);
    bfrag Axn;
    if (PREF) Axn = *(const bfrag*)sx_next;

    // gates = xacc(t) + h W_hh^T : 4 independent q-chains, 4-deep each
    facc acc[4];
#pragma unroll
    for (int q = 0; q < 4; ++q)
        acc[q] = __builtin_amdgcn_mfma_f32_16x16x32_bf16(Ah0, Bh[q][0], xacc[q], 0, 0, 0);
#pragma unroll
    for (int q = 0; q < 4; ++q)
        acc[q] = __builtin_amdgcn_mfma_f32_16x16x32_bf16(Ah1, Bh[q][1], acc[q], 0, 0, 0);
#pragma unroll
    for (int q = 0; q < 4; ++q)
        acc[q] = __builtin_amdgcn_mfma_f32_16x16x32_bf16(Ah2, Bh[q][2], acc[q], 0, 0, 0);
#pragma unroll
    for (int q = 0; q < 4; ++q)
        acc[q] = __builtin_amdgcn_mfma_f32_16x16x32_bf16(Ah3, Bh[q][3], acc[q], 0, 0, 0);

    // next step's x-part (fills matrix pipe during epilogue)
    if (PREF) {
#pragma unroll
        for (int q = 0; q < 4; ++q)
            xacc[q] = __builtin_amdgcn_mfma_f32_16x16x32_bf16(Axn, Bx[q], zf4, 0, 0, 0);
    }

    // spread: element (seq=lk, col=hcol) <- source lane lrsrc (lk=0), reg lk
    float z[4];
#pragma unroll
    for (int q = 0; q < 4; ++q) {
        const float s0 = __shfl(acc[q][0], lrsrc);
        const float s1 = __shfl(acc[q][1], lrsrc);
        const float s2 = __shfl(acc[q][2], lrsrc);
        const float s3 = __shfl(acc[q][3], lrsrc);
        const float t01 = b0 ? s1 : s0;
        const float t23 = b0 ? s3 : s2;
        z[q] = (b1 ? t23 : t01) + bias4[q];
    }

    // epilogue: 1 element/lane.  e^{-z} == 2^{-z'} (weights pre-scaled)
    const float ea = exp2f(-z[0]);
    const float ef = exp2f(-z[1]);
    const float eg = exp2f(-fabsf(z[2]));
    const float eo = exp2f(-z[3]);
    const float ig = __builtin_copysignf(
        (1.0f - eg) * __builtin_amdgcn_rcpf((1.0f + ea) * (1.0f + eg)), z[2]);
    cc = __builtin_amdgcn_rcpf(1.0f + ef) * cc + ig;
    const float ec = exp2f(-L2E2 * fabsf(cc));
    const float hv = __builtin_copysignf(
        (1.0f - ec) * __builtin_amdgcn_rcpf((1.0f + eo) * (1.0f + ec)), cc);
    *(short*)(shbase + WR + stoff) = (short)cvt_pk_bf16(hv, hv);
    __syncthreads();
}

// ---------------------------------------------------------------------------
// LSTM via MFMA: 224 blocks x 512 thr. Block owns 4 sequences; wave w owns
// h-columns [16w,16w+16) across all 4 gate sections.
// ---------------------------------------------------------------------------
__global__ __launch_bounds__(512, 1) void lstm_mfma_kernel(
    const float* __restrict__ x,         // [B, T, N, F] fp32
    const short* __restrict__ whh_bf,    // [512][128] bf16 (scaled)
    const short* __restrict__ wih_bf,    // [512][32]  bf16 (scaled, k>=16 zero)
    const float* __restrict__ bias,      // [512] fp32 (scaled)
    unsigned short* __restrict__ h_out)  // [896][128] bf16
{
    const int m0  = blockIdx.x * MBLK;   // global sequence base
    const int tid = threadIdx.x;
    const int w   = tid >> 6;            // wave 0..7
    const int l   = tid & 63;
    const int lr  = l & 15;              // tile row/col index
    const int lk  = l >> 4;              // k-block 0..3
    const int hcol = w * 16 + lr;        // this lane's h-column

    // LDS: sx [64 tl][4 seq][32 k] bf16 = 16 KB at +0 (k>=16 stays zero);
    //      sh double buffer at +16384 / +20480 (4 KB each, rows 0-3 valid).
    __shared__ __align__(16) char s_lds[24576];
    char* sxraw = s_lds;
    char* shbase = s_lds + 16384;

    // ---- load B fragments into registers (once) ----
    bfrag Bh[4][4];                      // [gate q][kstep]
    bfrag Bx[4];
    float bias4[4];
    #pragma unroll
    for (int q = 0; q < 4; ++q) {
        const int n = q * H_ + hcol;     // gate row in [0,512)
        #pragma unroll
        for (int ks = 0; ks < 4; ++ks)
            Bh[q][ks] = *(const bfrag*)(whh_bf + n * H_ + lk * 8 + ks * 32);
        Bx[q] = *(const bfrag*)(wih_bf + n * 32 + lk * 8);
        bias4[q] = bias[n];
    }
    const facc zf4 = (facc){0.f, 0.f, 0.f, 0.f};
    // Pin fragments as live registers: forbid rematerialization/sinking.
    #pragma unroll
    for (int q = 0; q < 4; ++q) {
        asm volatile("" : "+v"(Bx[q]));
        #pragma unroll
        for (int ks = 0; ks < 4; ++ks)
            asm volatile("" : "+v"(Bh[q][ks]));
    }

    float cc = 0.0f;
    facc  xacc[4];

    // loop-invariant LDS offsets
    const int swz = (lr & 7) << 4;
    const int xoff = lr * 64 + lk * 16;                // sx: no swizzle needed
    int hoff[4];
    #pragma unroll
    for (int ks = 0; ks < 4; ++ks)
        hoff[ks] = (lr * 256 + ks * 64 + lk * 16) ^ swz;
    const int stoff = (lk * 256 + hcol * 2) ^ ((lk & 7) << 4);
    const bool b0 = (lk & 1) != 0;
    const bool b1 = (lk & 2) != 0;

    // staging: 512 threads stage one (tl, seq, kb) 8-float frag per chunk
    const int stl = tid >> 3;            // 0..63
    const int sseq = (tid >> 1) & 3;
    const int skb = tid & 1;
    const int sg = m0 + sseq;
    const int bb = sg / N_;
    const int nn = sg % N_;
    const float* xq = x + ((((size_t)bb * T_ + stl) * N_ + nn) * F_ + skb * 8);
    const int sbyte = stl * 256 + sseq * 64 + skb * 16;
    const char* sxp = sxraw + xoff;

    // ---- zero LDS (sx pad region + dead rows persist; sh = h0 = 0) ----
    for (int i = tid; i < 24576 / 4; i += 512) ((int*)s_lds)[i] = 0;
    // prefetch chunk 0
    float4 pa = *(const float4*)(xq);
    float4 pb = *(const float4*)(xq + 4);
    __syncthreads();

    #pragma unroll 1
    for (int chunk = 0; chunk < T_ / TCH; ++chunk) {
        // ---- stage prefetched x chunk ----
        {
            uint4 o;
            o.x = cvt_pk_bf16(pa.x, pa.y); o.y = cvt_pk_bf16(pa.z, pa.w);
            o.z = cvt_pk_bf16(pb.x, pb.y); o.w = cvt_pk_bf16(pb.z, pb.w);
            *(uint4*)(sxraw + sbyte) = o;
        }
        if (chunk < T_ / TCH - 1) {      // prefetch next chunk (lands during compute)
            xq += TCH * N_ * F_;
            pa = *(const float4*)(xq);
            pb = *(const float4*)(xq + 4);
        }
        __syncthreads();

        // preamble: xacc for tl=0 of this chunk
        {
            const bfrag Ax = *(const bfrag*)sxp;
            #pragma unroll
            for (int q = 0; q < 4; ++q)
                xacc[q] = __builtin_amdgcn_mfma_f32_16x16x32_bf16(Ax, Bx[q], zf4, 0, 0, 0);
        }

        #pragma unroll 1
        for (int tl = 0; tl < TCH - 2; tl += 2) {
            lstm_step<16384, 20480, true>(s_lds, sxp + (tl + 1) * 256, Bh, Bx, zf4,
                                          xacc, cc, hoff, stoff, lr, b0, b1, bias4);
            lstm_step<20480, 16384, true>(s_lds, sxp + (tl + 2) * 256, Bh, Bx, zf4,
                                          xacc, cc, hoff, stoff, lr, b0, b1, bias4);
        }
        lstm_step<16384, 20480, true >(s_lds, sxp + (TCH - 1) * 256, Bh, Bx, zf4,
                                       xacc, cc, hoff, stoff, lr, b0, b1, bias4);
        lstm_step<20480, 16384, false>(s_lds, nullptr, Bh, Bx, zf4,
                                       xacc, cc, hoff, stoff, lr, b0, b1, bias4);
    }

    // final h is in buffer at +16384 (even step count); write out bf16
    {
        const int m = tid >> 7, col = tid & 127;
        const int byte = (m * 256 + col * 2) ^ ((m & 7) << 4);
        h_out[(size_t)(m0 + m) * H_ + col] = *(unsigned short*)(shbase + byte);
    }
}

// ---------------------------------------------------------------------------
// Head kernel: one block per batch element b. GCN + linears + sigmoid.
// ---------------------------------------------------------------------------
__global__ __launch_bounds__(256) void head_kernel(
    const float* __restrict__ adj,
    const float* __restrict__ W_gcn, const float* __restrict__ b_gcn,
    const float* __restrict__ W_out, const float* __restrict__ b_out,
    const float* __restrict__ W_lin1, const float* __restrict__ b_lin1,
    const unsigned short* __restrict__ h_in,   // [896][128] bf16
    float* __restrict__ out)                   // [B, 28]
{
    const int b   = blockIdx.x;
    const int tid = threadIdx.x;

    __shared__ float s_A[N_][N_];
    __shared__ float s_d[N_];
    __shared__ float s_h[N_][H_];
    __shared__ float s_xg[N_][H_];
    __shared__ float s_g1[N_][64];
    __shared__ float s_s[N_];

    for (int idx = tid; idx < N_ * H_; idx += 256)
        s_h[idx >> 7][idx & 127] = bf2f(h_in[(size_t)b * N_ * H_ + idx]);

    if (tid < N_) {
        float sum = 0.0f;
        for (int j = 0; j < N_; ++j)
            sum += adj[tid * N_ + j] + (tid == j ? 1.0f : 0.0f);
        s_d[tid] = rsqrtf(sum);
    }
    __syncthreads();

    if (tid < N_ * N_) {
        const int i = tid / N_, j = tid % N_;
        const float a = adj[i * N_ + j] + (i == j ? 1.0f : 0.0f);
        s_A[i][j] = s_d[i] * a * s_d[j];
    }
    __syncthreads();

    for (int idx = tid; idx < N_ * H_; idx += 256) {
        const int i = idx >> 7, k = idx & 127;
        float acc = 0.0f;
        #pragma unroll
        for (int j = 0; j < N_; ++j) acc += s_A[i][j] * s_h[j][k];
        s_xg[i][k] = acc;
    }
    __syncthreads();

    for (int idx = tid; idx < N_ * 64; idx += 256) {
        const int i = idx >> 6, q = idx & 63;
        float a0 = 0.f, a1 = 0.f, a2 = 0.f, a3 = 0.f;
        #pragma unroll
        for (int k = 0; k < H_; k += 4) {
            a0 += s_xg[i][k+0] * W_gcn[q * H_ + k+0];
            a1 += s_xg[i][k+1] * W_gcn[q * H_ + k+1];
            a2 += s_xg[i][k+2] * W_gcn[q * H_ + k+2];
            a3 += s_xg[i][k+3] * W_gcn[q * H_ + k+3];
        }
        const float acc = b_gcn[q] + ((a0 + a1) + (a2 + a3));
        s_g1[i][q] = fmaxf(acc, 0.0f);
    }
    __syncthreads();

    if (tid < N_) {
        float acc = b_out[0];
        #pragma unroll
        for (int q = 0; q < 64; ++q) acc += s_g1[tid][q] * W_out[q];
        s_s[tid] = acc;
    }
    __syncthreads();

    if (tid < 28) {
        float acc = b_lin1[tid];
        #pragma unroll
        for (int i = 0; i < N_; ++i) acc += s_s[i] * W_lin1[tid * N_ + i];
        out[b * 28 + tid] = 1.0f / (1.0f + __expf(-acc));
    }
}

extern "C" void kernel_launch(void* const* d_in, const int* in_sizes, int n_in,
                              void* d_out, int out_size, void* d_ws, size_t ws_size,
                              hipStream_t stream) {
    const float* x      = (const float*)d_in[0];
    const float* adj    = (const float*)d_in[1];
    const float* W_ih   = (const float*)d_in[2];
    const float* W_hh   = (const float*)d_in[3];
    const float* b_ih   = (const float*)d_in[4];
    const float* b_hh   = (const float*)d_in[5];
    const float* W_gcn  = (const float*)d_in[6];
    const float* b_gcn  = (const float*)d_in[7];
    const float* W_out  = (const float*)d_in[8];
    const float* b_out  = (const float*)d_in[9];
    const float* W_lin1 = (const float*)d_in[10];
    const float* b_lin1 = (const float*)d_in[11];
    float* out = (float*)d_out;

    // workspace layout (bytes): total 395264
    char* ws = (char*)d_ws;
    short*          whh_bf = (short*)(ws);                    // 512*128*2 = 131072
    short*          wih_bf = (short*)(ws + 131072);           // 512*32*2  =  32768
    float*          bias   = (float*)(ws + 163840);           // 512*4     =   2048
    unsigned short* h_last = (unsigned short*)(ws + 165888);  // 896*128*2 = 229376

    prep_kernel<<<128, 512, 0, stream>>>(W_ih, W_hh, b_ih, b_hh, whh_bf, wih_bf, bias);
    lstm_mfma_kernel<<<NBLK, 512, 0, stream>>>(x, whh_bf, wih_bf, bias, h_last);
    head_kernel<<<B_, 256, 0, stream>>>(adj, W_gcn, b_gcn, W_out, b_out,
                                        W_lin1, b_lin1, h_last, out);
}